// Round 8
// baseline (486.793 us; speedup 1.0000x reference)
//
#include <hip/hip_runtime.h>
#include <hip/hip_bf16.h>

typedef __hip_bfloat16 bf16;
typedef __attribute__((ext_vector_type(8))) short short8;
typedef __attribute__((ext_vector_type(4))) float f32x4;
typedef __attribute__((ext_vector_type(4))) unsigned short u16x4;

#define DMODEL 1280
#define DFFN   5120
#define BATCH  4
#define SEQ    1024
#define NHEAD  20
#define HDIM   64
#define NROWS  (BATCH * SEQ)   // 4096

// async global->LDS, 16B per lane; HW dest = wave-uniform base + lane*16
#define GLDS(g, l) __builtin_amdgcn_global_load_lds(                            \
    (const __attribute__((address_space(1))) void*)(g),                         \
    (__attribute__((address_space(3))) void*)(l), 16, 0, 0)

// inline-asm LDS read: invisible to compiler alias analysis, so it cannot
// insert a conservative s_waitcnt vmcnt(0) ordering vs global_load_lds.
static __device__ __forceinline__ short8 ds_read128(const bf16* p) {
    short8 r;
    asm volatile("ds_read_b128 %0, %1"
        : "=v"(r)
        : "v"((const __attribute__((address_space(3))) bf16*)p));
    return r;
}

// ---------------------------------------------------------------------------
// Unified prep: 6 weight transposes (fp32 [K,N] -> bf16 [N,K]) + bias pack
// ---------------------------------------------------------------------------
__global__ __launch_bounds__(256) void prep_all(
    const float* __restrict__ wq, const float* __restrict__ wk,
    const float* __restrict__ wv, const float* __restrict__ wo,
    const float* __restrict__ fc1w, const float* __restrict__ fc2w,
    const float* __restrict__ bq, const float* __restrict__ bk,
    const float* __restrict__ bv,
    bf16* __restrict__ wqkvt, bf16* __restrict__ wot,
    bf16* __restrict__ fc1t, bf16* __restrict__ fc2t,
    float* __restrict__ bqkv)
{
    const int bid = blockIdx.x;
    if (bid == 19200) {
        for (int i = threadIdx.x; i < DMODEL; i += 256) {
            bqkv[i]              = bq[i];
            bqkv[DMODEL + i]     = bk[i];
            bqkv[2 * DMODEL + i] = bv[i];
        }
        return;
    }
    const float* in;
    bf16* out;
    int K, N, n0, k0;
    if (bid < 6400) {
        const int mat = bid / 1600, rem = bid % 1600;
        K = DMODEL; N = DMODEL;
        n0 = (rem % 40) * 32; k0 = (rem / 40) * 32;
        switch (mat) {
            case 0:  in = wq; out = wqkvt; break;
            case 1:  in = wk; out = wqkvt + (size_t)DMODEL * DMODEL; break;
            case 2:  in = wv; out = wqkvt + (size_t)2 * DMODEL * DMODEL; break;
            default: in = wo; out = wot; break;
        }
    } else if (bid < 12800) {
        const int rem = bid - 6400;
        K = DMODEL; N = DFFN; in = fc1w; out = fc1t;
        n0 = (rem % 160) * 32; k0 = (rem / 160) * 32;
    } else {
        const int rem = bid - 12800;
        K = DFFN; N = DMODEL; in = fc2w; out = fc2t;
        n0 = (rem % 40) * 32; k0 = (rem / 40) * 32;
    }
    __shared__ float tile[32][33];
    const int tx = threadIdx.x & 31;
    const int ty = threadIdx.x >> 5;   // 0..7
    for (int i = 0; i < 32; i += 8)
        tile[ty + i][tx] = in[(size_t)(k0 + ty + i) * N + (n0 + tx)];
    __syncthreads();
    for (int i = 0; i < 32; i += 8)
        out[(size_t)(n0 + ty + i) * K + (k0 + tx)] = __float2bfloat16(tile[tx][ty + i]);
}

// ---------------------------------------------------------------------------
// LayerNorm over last dim (1280), one block (256 thr) per row, bf16 out
// ---------------------------------------------------------------------------
__global__ __launch_bounds__(256) void ln_bf16(
    const float* __restrict__ x, const float* __restrict__ sc,
    const float* __restrict__ of, bf16* __restrict__ out)
{
    const int row = blockIdx.x;
    const float* xr = x + (size_t)row * DMODEL;
    float v[5];
    float s = 0.f, s2 = 0.f;
    for (int i = 0; i < 5; ++i) {
        v[i] = xr[threadIdx.x + i * 256];
        s += v[i];
        s2 += v[i] * v[i];
    }
    for (int off = 1; off < 64; off <<= 1) {
        s  += __shfl_xor(s, off);
        s2 += __shfl_xor(s2, off);
    }
    __shared__ float red[2][4];
    const int wid = threadIdx.x >> 6;
    if ((threadIdx.x & 63) == 0) { red[0][wid] = s; red[1][wid] = s2; }
    __syncthreads();
    s  = red[0][0] + red[0][1] + red[0][2] + red[0][3];
    s2 = red[1][0] + red[1][1] + red[1][2] + red[1][3];
    const float mean = s * (1.0f / DMODEL);
    const float var  = s2 * (1.0f / DMODEL) - mean * mean;
    const float rstd = rsqrtf(var + 1e-5f);
    for (int i = 0; i < 5; ++i) {
        const int c = threadIdx.x + i * 256;
        const float y = (v[i] - mean) * rstd * sc[c] + of[c];
        out[(size_t)row * DMODEL + c] = __float2bfloat16(y);
    }
}

// ---------------------------------------------------------------------------
// Fused: x1 = P0 + P1 + bias + res;  h2 = LayerNorm(x1)*sc + of  (bf16)
// ---------------------------------------------------------------------------
__global__ __launch_bounds__(256) void reduce2_ln(
    const float* __restrict__ P, const float* __restrict__ bias,
    const float* __restrict__ res, float* __restrict__ x1,
    const float* __restrict__ sc, const float* __restrict__ of,
    bf16* __restrict__ h2)
{
    const int row = blockIdx.x;
    const size_t base = (size_t)row * DMODEL;
    const int MN = NROWS * DMODEL;
    float v[5];
    float s = 0.f, s2 = 0.f;
    for (int i = 0; i < 5; ++i) {
        const int c = threadIdx.x + i * 256;
        const float val = P[base + c] + P[MN + base + c] + bias[c] + res[base + c];
        v[i] = val;
        x1[base + c] = val;
        s += val;
        s2 += val * val;
    }
    for (int off = 1; off < 64; off <<= 1) {
        s  += __shfl_xor(s, off);
        s2 += __shfl_xor(s2, off);
    }
    __shared__ float red[2][4];
    const int wid = threadIdx.x >> 6;
    if ((threadIdx.x & 63) == 0) { red[0][wid] = s; red[1][wid] = s2; }
    __syncthreads();
    s  = red[0][0] + red[0][1] + red[0][2] + red[0][3];
    s2 = red[1][0] + red[1][1] + red[1][2] + red[1][3];
    const float mean = s * (1.0f / DMODEL);
    const float var  = s2 * (1.0f / DMODEL) - mean * mean;
    const float rstd = rsqrtf(var + 1e-5f);
    for (int i = 0; i < 5; ++i) {
        const int c = threadIdx.x + i * 256;
        const float y = (v[i] - mean) * rstd * sc[c] + of[c];
        h2[base + c] = __float2bfloat16(y);
    }
}

// ---------------------------------------------------------------------------
// gemm8p: m201-style 8-phase 256x256 GEMM, BK=64, 8 waves (2M x 4N),
// per-wave 128x64 output (acc[8][4]), 128 KB dynamic LDS, 1 block/CU.
//
// Rounds 4-7 post-mortem: every 64x64-per-wave variant plateaus at 82-94us
// (FLOP/LDS-byte=32 caps MfmaUtil at ~45% on LDS BW alone).  128x64 wave
// tiles raise that to ~71%; the 8-phase counted-vmcnt schedule (never 0
// mid-loop) keeps loads in flight across barriers.
//
// Per K-tile t (slot sl=t&1), 4 quadrant-phases (mq,nq of the wave's 128x64):
//  P1 q(0,0): 16 ds_reads (A-mq0 8, B-nq0 4, B-nq1 4); stage B(t+1) [4 GLDS,
//             slot sl^1, last read K-tile t-1 -> many barriers ago];
//             barrier; lgkmcnt(0)+SGB; 16 MFMA; barrier.
//  P2 q(0,1): pure MFMA from held regs (af mq0 x b1).  No barriers.
//  P3 q(1,1): 8 ds_reads (A-mq1); barrier; lgkmcnt(0)+SGB; 16 MFMA; barrier.
//  P4 q(1,0): stage A(t+2) [4 GLDS, slot sl — free after P3's confirmed
//             reads + barrier]; 16 MFMA (af mq1 x b0); boundary:
//             vmcnt(4) [A(t+2) may fly; B(t+1)/older forced]; barrier.
// Prologue stages A(0),B(0),A(1),B(1); vmcnt(8); barrier.
// Swizzle: phys_chunk = logical ^ ((row>>1)&7) — 16 lanes spread over 8
// chunks, 2/chunk = free (extends the measured-0-conflict BK=32 scheme).
// EPI 0: bf16 = acc+bias | EPI 2: gelu | EPI 3: f32 partial (split-K z)
// ---------------------------------------------------------------------------
template <int EPI>
__global__ __launch_bounds__(512, 2) void gemm8p(
    const bf16* __restrict__ A, const bf16* __restrict__ Bt,
    const float* __restrict__ bias,
    bf16* __restrict__ Cb, float* __restrict__ Cf,
    int M, int N, int K, int klen)
{
    extern __shared__ char smem[];
    constexpr int SLOT = 256 * 64;                 // elems per slot
    bf16* As0 = (bf16*)smem;                       // [2][256][64]
    bf16* Bs0 = As0 + 2 * SLOT;                    // [2][256][64]

    const int m0 = blockIdx.x * 256;
    const int n0 = blockIdx.y * 256;
    const int z  = blockIdx.z;
    const int kbeg = z * klen;

    const int tid  = threadIdx.x;
    const int lane = tid & 63;
    const int wid  = tid >> 6;            // 0..7
    const int wm   = (wid >> 2) * 128;    // 2 m-groups of 128
    const int wn   = (wid & 3) * 64;      // 4 n-groups of 64
    const int l15  = lane & 15;
    const int lq   = lane >> 4;

    f32x4 acc[8][4];
    #pragma unroll
    for (int i = 0; i < 8; ++i)
        #pragma unroll
        for (int j = 0; j < 4; ++j)
            acc[i][j] = (f32x4){0.f, 0.f, 0.f, 0.f};

    // ---- staging addressing: one GLDS call-set = 4 insts, rows q*64+wid*8+..
    const int srow = wid * 8 + (lane >> 3);                       // 0..63
    const int scl  = (lane & 7) ^ ((wid & 1) << 2) ^ (lane >> 4); // pre-swz src chunk
    const bf16* aT = A  + (size_t)(m0 + srow) * K + kbeg + scl * 8;
    const bf16* bT = Bt + (size_t)(n0 + srow) * K + kbeg + scl * 8;
    const size_t rs64 = (size_t)64 * K;
    const int dwave = (wid * 8) * 64;     // wave-uniform LDS elem offset

    auto STAGE_A = [&](int tt) {
        const bf16* s = aT + (size_t)tt * 64;
        bf16* d = As0 + (tt & 1) * SLOT + dwave;
        GLDS(s,            d);
        GLDS(s +     rs64, d +  64 * 64);
        GLDS(s + 2 * rs64, d + 128 * 64);
        GLDS(s + 3 * rs64, d + 192 * 64);
    };
    auto STAGE_B = [&](int tt) {
        const bf16* s = bT + (size_t)tt * 64;
        bf16* d = Bs0 + (tt & 1) * SLOT + dwave;
        GLDS(s,            d);
        GLDS(s +     rs64, d +  64 * 64);
        GLDS(s + 2 * rs64, d + 128 * 64);
        GLDS(s + 3 * rs64, d + 192 * 64);
    };

    // ---- fragment read addressing
    const int rkey = (l15 >> 1) & 7;
    const int pc0  = ((0 + lq) ^ rkey) * 8;   // ks=0 phys elem offset
    const int pc1  = ((4 + lq) ^ rkey) * 8;   // ks=1

    // prologue: tiles 0,1 (A then B per tile; oldest 8 = tile 0)
    STAGE_A(0); STAGE_B(0);
    STAGE_A(1); STAGE_B(1);
    asm volatile("s_waitcnt vmcnt(8)" ::: "memory");
    __builtin_amdgcn_s_barrier();

    const int T = klen / 64;
    for (int t = 0; t < T; ++t) {
        const int sl = t & 1;
        bf16* Ac = As0 + sl * SLOT;
        bf16* Bc = Bs0 + sl * SLOT;

        short8 af[4][2], b0[2][2], b1[2][2];

        // ---- P1: reads (16) + stage B(t+1) ----
        #pragma unroll
        for (int mt = 0; mt < 4; ++mt) {
            const bf16* p = Ac + (size_t)(wm + mt * 16 + l15) * 64;
            af[mt][0] = ds_read128(p + pc0);
            af[mt][1] = ds_read128(p + pc1);
        }
        #pragma unroll
        for (int nt = 0; nt < 2; ++nt) {
            const bf16* p = Bc + (size_t)(wn + nt * 16 + l15) * 64;
            b0[nt][0] = ds_read128(p + pc0);
            b0[nt][1] = ds_read128(p + pc1);
        }
        #pragma unroll
        for (int nt = 0; nt < 2; ++nt) {
            const bf16* p = Bc + (size_t)(wn + 32 + nt * 16 + l15) * 64;
            b1[nt][0] = ds_read128(p + pc0);
            b1[nt][1] = ds_read128(p + pc1);
        }
        if (t >= 1 && t + 1 < T) STAGE_B(t + 1);
        __builtin_amdgcn_s_barrier();
        asm volatile("s_waitcnt lgkmcnt(0)" ::: "memory");
        __builtin_amdgcn_sched_barrier(0);
        __builtin_amdgcn_s_setprio(1);
        #pragma unroll
        for (int mt = 0; mt < 4; ++mt)
            #pragma unroll
            for (int nt = 0; nt < 2; ++nt) {
                acc[mt][nt] = __builtin_amdgcn_mfma_f32_16x16x32_bf16(
                    af[mt][0], b0[nt][0], acc[mt][nt], 0, 0, 0);
                acc[mt][nt] = __builtin_amdgcn_mfma_f32_16x16x32_bf16(
                    af[mt][1], b0[nt][1], acc[mt][nt], 0, 0, 0);
            }
        __builtin_amdgcn_s_setprio(0);
        __builtin_amdgcn_s_barrier();

        // ---- P2: q(0,1), pure MFMA from held regs ----
        __builtin_amdgcn_s_setprio(1);
        #pragma unroll
        for (int mt = 0; mt < 4; ++mt)
            #pragma unroll
            for (int nt = 0; nt < 2; ++nt) {
                acc[mt][2 + nt] = __builtin_amdgcn_mfma_f32_16x16x32_bf16(
                    af[mt][0], b1[nt][0], acc[mt][2 + nt], 0, 0, 0);
                acc[mt][2 + nt] = __builtin_amdgcn_mfma_f32_16x16x32_bf16(
                    af[mt][1], b1[nt][1], acc[mt][2 + nt], 0, 0, 0);
            }
        __builtin_amdgcn_s_setprio(0);

        // ---- P3: reads (8, A mq1) + q(1,1) ----
        #pragma unroll
        for (int mt = 0; mt < 4; ++mt) {
            const bf16* p = Ac + (size_t)(wm + 64 + mt * 16 + l15) * 64;
            af[mt][0] = ds_read128(p + pc0);
            af[mt][1] = ds_read128(p + pc1);
        }
        __builtin_amdgcn_s_barrier();
        asm volatile("s_waitcnt lgkmcnt(0)" ::: "memory");
        __builtin_amdgcn_sched_barrier(0);
        __builtin_amdgcn_s_setprio(1);
        #pragma unroll
        for (int mt = 0; mt < 4; ++mt)
            #pragma unroll
            for (int nt = 0; nt < 2; ++nt) {
                acc[4 + mt][2 + nt] = __builtin_amdgcn_mfma_f32_16x16x32_bf16(
                    af[mt][0], b1[nt][0], acc[4 + mt][2 + nt], 0, 0, 0);
                acc[4 + mt][2 + nt] = __builtin_amdgcn_mfma_f32_16x16x32_bf16(
                    af[mt][1], b1[nt][1], acc[4 + mt][2 + nt], 0, 0, 0);
            }
        __builtin_amdgcn_s_setprio(0);
        __builtin_amdgcn_s_barrier();

        // ---- P4: stage A(t+2) + q(1,0) + K-tile boundary ----
        if (t + 2 < T) STAGE_A(t + 2);
        __builtin_amdgcn_s_setprio(1);
        #pragma unroll
        for (int mt = 0; mt < 4; ++mt)
            #pragma unroll
            for (int nt = 0; nt < 2; ++nt) {
                acc[4 + mt][nt] = __builtin_amdgcn_mfma_f32_16x16x32_bf16(
                    af[mt][0], b0[nt][0], acc[4 + mt][nt], 0, 0, 0);
                acc[4 + mt][nt] = __builtin_amdgcn_mfma_f32_16x16x32_bf16(
                    af[mt][1], b0[nt][1], acc[4 + mt][nt], 0, 0, 0);
            }
        __builtin_amdgcn_s_setprio(0);
        if (t + 1 < T) {
            if (t + 2 < T) asm volatile("s_waitcnt vmcnt(4)" ::: "memory");
            else           asm volatile("s_waitcnt vmcnt(0)" ::: "memory");
            __builtin_amdgcn_s_barrier();
        }
    }

    // epilogue: D row = lq*4 + r, col = l15  (verified m89 layout; identical
    // to round-2 gemm256 epilogue which passed refcheck)
    float* Pf = Cf + (size_t)z * M * N;
    #pragma unroll
    for (int mt = 0; mt < 8; ++mt)
        #pragma unroll
        for (int nt = 0; nt < 4; ++nt)
            #pragma unroll
            for (int r = 0; r < 4; ++r) {
                const int row = m0 + wm + mt * 16 + lq * 4 + r;
                const int col = n0 + wn + nt * 16 + l15;
                if (EPI == 0) {
                    const float v = acc[mt][nt][r] + bias[col];
                    Cb[(size_t)row * N + col] = __float2bfloat16(v);
                } else if (EPI == 2) {
                    const float v = acc[mt][nt][r] + bias[col];
                    const float g = 0.5f * v * (1.0f + erff(v * 0.70710678118654752f));
                    Cb[(size_t)row * N + col] = __float2bfloat16(g);
                } else {
                    Pf[(size_t)row * N + col] = acc[mt][nt][r];
                }
            }
}

// ---------------------------------------------------------------------------
// split-K=2 reduce: out = P0 + P1 + bias + res   (float4 vectorized)
// ---------------------------------------------------------------------------
__global__ __launch_bounds__(256) void reduce2(
    const float* __restrict__ P, const float* __restrict__ bias,
    const float* __restrict__ res, float* __restrict__ out, int MN, int N)
{
    const int i = (blockIdx.x * 256 + threadIdx.x) * 4;
    if (i >= MN) return;
    const float4 p0 = *(const float4*)(P + i);
    const float4 p1 = *(const float4*)(P + MN + i);
    const float4 r  = *(const float4*)(res + i);
    const float4 b  = *(const float4*)(bias + (i % N));
    float4 o;
    o.x = p0.x + p1.x + r.x + b.x;
    o.y = p0.y + p1.y + r.y + b.y;
    o.z = p0.z + p1.z + r.z + b.z;
    o.w = p0.w + p1.w + r.w + b.w;
    *(float4*)(out + i) = o;
}

// ---------------------------------------------------------------------------
// Flash attention v3 (unchanged): transposed-S formulation.
// ---------------------------------------------------------------------------
__global__ __launch_bounds__(256) void flash_attn(
    const bf16* __restrict__ qb, const bf16* __restrict__ kb,
    const bf16* __restrict__ vb, bf16* __restrict__ ob, int ldq)
{
    __shared__ bf16 Ks[2][64][64];    // 16 KB  [kv][d]
    __shared__ bf16 Vt[64][64];       // 8 KB   [d][kv]
    __shared__ bf16 Ps[4][16][64];    // 8 KB   per-wave P^T as [q][kv]

    const int bh = blockIdx.y;
    const int b  = bh / NHEAD;
    const int hh = bh % NHEAD;
    const int q0 = blockIdx.x * 64;
    const int tid  = threadIdx.x;
    const int lane = tid & 63;
    const int wid  = tid >> 6;
    const int l15  = lane & 15;
    const int lq   = lane >> 4;
    const int key  = l15 & 7;

    short8 qf[2];
    {
        const bf16* qp = qb + (size_t)(b * SEQ + q0 + wid * 16 + l15) * ldq
                         + hh * HDIM + lq * 8;
        for (int kk = 0; kk < 2; ++kk) {
            union { short8 v; bf16 h[8]; } u;
            u.v = *(const short8*)(qp + kk * 32);
            for (int j = 0; j < 8; ++j)
                u.h[j] = __float2bfloat16(__bfloat162float(u.h[j]) * 0.125f);
            qf[kk] = u.v;
        }
    }

    f32x4 o[4];   // O^T: row d = dt*16 + lq*4 + r, col q = l15
    for (int dt = 0; dt < 4; ++dt) o[dt] = (f32x4){0.f, 0.f, 0.f, 0.f};
    float lsum = 0.f;

    const int krow  = wid * 8 + (lane >> 3);
    const int kcgl8 = ((lane & 7) ^ (krow & 7)) * 8;
    const int kcph8 = (lane & 7) * 8;
    const int vd0  = (tid & 15) * 4;
    const int vkv0 = (tid >> 4) * 4;

    const bf16* kBase = kb + (size_t)(b * SEQ + krow) * ldq + hh * HDIM + kcgl8;
    const bf16* vBase = vb + (size_t)(b * SEQ + vkv0) * ldq + hh * HDIM + vd0;

    GLDS(kBase,                    &Ks[0][krow][kcph8]);
    GLDS(kBase + (size_t)32 * ldq, &Ks[0][krow + 32][kcph8]);
    u16x4 vr[4];
    for (int j = 0; j < 4; ++j)
        vr[j] = *(const u16x4*)(vBase + (size_t)j * ldq);

    const int nIter = SEQ / 64;
    for (int it = 0; it < nIter; ++it) {
        const int buf = it & 1;
        __syncthreads();
        for (int i = 0; i < 4; ++i) {
            u16x4 w = { vr[0][i], vr[1][i], vr[2][i], vr[3][i] };
            const int p = ((vkv0 >> 3) ^ ((vd0 + i) & 7)) * 8 + (vkv0 & 7);
            *(u16x4*)(&Vt[vd0 + i][p]) = w;
        }
        __syncthreads();

        if (it + 1 < nIter) {
            const size_t off = (size_t)(it + 1) * 64 * ldq;
            GLDS(kBase + off,                    &Ks[buf ^ 1][krow][kcph8]);
            GLDS(kBase + off + (size_t)32 * ldq, &Ks[buf ^ 1][krow + 32][kcph8]);
            for (int j = 0; j < 4; ++j)
                vr[j] = *(const u16x4*)(vBase + off + (size_t)j * ldq);
        }

        // ---- S^T = K Q^T ----
        for (int mt = 0; mt < 4; ++mt) {
            const bf16* kp = &Ks[buf][mt * 16 + l15][0];
            const short8 kf0 = *(const short8*)(kp + ((0 + lq) ^ key) * 8);
            const short8 kf1 = *(const short8*)(kp + ((4 + lq) ^ key) * 8);
            f32x4 a = (f32x4){0.f, 0.f, 0.f, 0.f};
            a = __builtin_amdgcn_mfma_f32_16x16x32_bf16(kf0, qf[0], a, 0, 0, 0);
            a = __builtin_amdgcn_mfma_f32_16x16x32_bf16(kf1, qf[1], a, 0, 0, 0);
            union { u16x4 v; bf16 h[4]; } pk;
            for (int r = 0; r < 4; ++r) {
                const float p = __expf(a[r]);
                lsum += p;
                pk.h[r] = __float2bfloat16(p);
            }
            const int pc = ((mt * 2 + (lq >> 1)) ^ key) * 8 + (lq & 1) * 4;
            *(u16x4*)(&Ps[wid][l15][pc]) = pk.v;
        }

        // ---- O^T += V^T P^T ----
        for (int kk = 0; kk < 2; ++kk) {
            const short8 pf = *(const short8*)(
                &Ps[wid][l15][((lq + 4 * kk) ^ key) * 8]);
            for (int dt = 0; dt < 4; ++dt) {
                const short8 vf = *(const short8*)(
                    &Vt[dt * 16 + l15][((lq + 4 * kk) ^ key) * 8]);
                o[dt] = __builtin_amdgcn_mfma_f32_16x16x32_bf16(
                    vf, pf, o[dt], 0, 0, 0);
            }
        }
    }

    lsum += __shfl_xor(lsum, 16);
    lsum += __shfl_xor(lsum, 32);
    const float inv_l = 1.0f / lsum;

    const size_t qrow = (size_t)(b * SEQ + q0 + wid * 16 + l15);
    for (int dt = 0; dt < 4; ++dt) {
        union { u16x4 v; bf16 h[4]; } w;
        for (int r = 0; r < 4; ++r)
            w.h[r] = __float2bfloat16(o[dt][r] * inv_l);
        *(u16x4*)(ob + qrow * DMODEL + hh * HDIM + dt * 16 + lq * 4) = w.v;
    }
}

// ---------------------------------------------------------------------------
extern "C" void kernel_launch(void* const* d_in, const int* in_sizes, int n_in,
                              void* d_out, int out_size, void* d_ws, size_t ws_size,
                              hipStream_t stream)
{
    (void)in_sizes; (void)n_in; (void)out_size; (void)ws_size;
    const float* x    = (const float*)d_in[0];
    const float* ln1s = (const float*)d_in[1];
    const float* ln1o = (const float*)d_in[2];
    const float* wq   = (const float*)d_in[3];
    const float* bq   = (const float*)d_in[4];
    const float* wk   = (const float*)d_in[5];
    const float* bk   = (const float*)d_in[6];
    const float* wv   = (const float*)d_in[7];
    const float* bv   = (const float*)d_in[8];
    const float* wo   = (const float*)d_in[9];
    const float* bo   = (const float*)d_in[10];
    const float* ln2s = (const float*)d_in[11];
    const float* ln2o = (const float*)d_in[12];
    const float* fc1w = (const float*)d_in[13];
    const float* fc1b = (const float*)d_in[14];
    const float* fc2w = (const float*)d_in[15];
    const float* fc2b = (const float*)d_in[16];
    float* out = (float*)d_out;

    char* wp = (char*)d_ws;
    auto alloc = [&](size_t n) { char* p = wp; wp += (n + 255) & ~(size_t)255; return p; };
    bf16*  wqkvt = (bf16*)alloc((size_t)3 * DMODEL * DMODEL * 2);
    bf16*  wot   = (bf16*)alloc((size_t)DMODEL * DMODEL * 2);
    bf16*  fc1t  = (bf16*)alloc((size_t)DFFN * DMODEL * 2);    // [5120][1280]
    bf16*  fc2t  = (bf16*)alloc((size_t)DMODEL * DFFN * 2);    // [1280][5120]
    float* bqkv  = (float*)alloc((size_t)3 * DMODEL * 4);
    // region A: h | qkv | attn ; partials (split-K=2, 41.94 MB) alias h+qkv
    char*  regA  = alloc((size_t)NROWS * DMODEL * 2      // h
                       + (size_t)NROWS * 3 * DMODEL * 2  // qkv
                       + (size_t)NROWS * DMODEL * 2);    // attn
    bf16*  h     = (bf16*)regA;
    bf16*  qkv   = (bf16*)(regA + (size_t)NROWS * DMODEL * 2);
    bf16*  attn  = (bf16*)(regA + (size_t)NROWS * 4 * DMODEL * 2);
    float* part  = (float*)regA;                         // 2 * NROWS*DMODEL f32
    bf16*  h2    = (bf16*)alloc((size_t)NROWS * DMODEL * 2);
    bf16*  g     = (bf16*)alloc((size_t)NROWS * DFFN * 2);
    float* x1    = out;   // post-attention residual lives in d_out

    prep_all<<<19201, 256, 0, stream>>>(
        wq, wk, wv, wo, fc1w, fc2w, bq, bk, bv,
        wqkvt, wot, fc1t, fc2t, bqkv);

    ln_bf16<<<NROWS, 256, 0, stream>>>(x, ln1s, ln1o, h);

    // fused QKV: [4096,1280] @ [1280,3840] -> qkv  (256^2 tiles, 240 blocks)
    gemm8p<0><<<dim3(NROWS / 256, 3 * DMODEL / 256, 1), 512, 131072, stream>>>(
        h, wqkvt, bqkv, qkv, nullptr, NROWS, 3 * DMODEL, DMODEL, DMODEL);

    flash_attn<<<dim3(SEQ / 64, BATCH * NHEAD), 256, 0, stream>>>(
        qkv, qkv + DMODEL, qkv + 2 * DMODEL, attn, 3 * DMODEL);

    // WO split-K=2 -> partials (256^2 tiles, 160 blocks), then fused
    // reduce(+bo+x)+LN2 -> x1, h2
    gemm8p<3><<<dim3(NROWS / 256, DMODEL / 256, 2), 512, 131072, stream>>>(
        attn, wot, nullptr, nullptr, part, NROWS, DMODEL, DMODEL, DMODEL / 2);
    reduce2_ln<<<NROWS, 256, 0, stream>>>(part, bo, x, x1, ln2s, ln2o, h2);

    // FC1 + exact GELU (256^2 tiles, 320 blocks)
    gemm8p<2><<<dim3(NROWS / 256, DFFN / 256, 1), 512, 131072, stream>>>(
        h2, fc1t, fc1b, g, nullptr, NROWS, DFFN, DMODEL, DMODEL);

    // FC2 split-K=2 -> partials (256^2 tiles, 160 blocks), then reduce
    gemm8p<3><<<dim3(NROWS / 256, DMODEL / 256, 2), 512, 131072, stream>>>(
        g, fc2t, nullptr, nullptr, part, NROWS, DMODEL, DFFN, DFFN / 2);
    reduce2<<<(NROWS * DMODEL / 4 + 255) / 256, 256, 0, stream>>>(
        part, fc2b, x1, out, NROWS * DMODEL, DMODEL);
}

// Round 9
// 462.592 us; speedup vs baseline: 1.0523x; 1.0523x over previous
//
#include <hip/hip_runtime.h>
#include <hip/hip_bf16.h>

typedef __hip_bfloat16 bf16;
typedef __attribute__((ext_vector_type(8))) short short8;
typedef __attribute__((ext_vector_type(4))) float f32x4;
typedef __attribute__((ext_vector_type(4))) unsigned short u16x4;

#define DMODEL 1280
#define DFFN   5120
#define BATCH  4
#define SEQ    1024
#define NHEAD  20
#define HDIM   64
#define NROWS  (BATCH * SEQ)   // 4096

// async global->LDS, 16B per lane; HW dest = wave-uniform base + lane*16
#define GLDS(g, l) __builtin_amdgcn_global_load_lds(                            \
    (const __attribute__((address_space(1))) void*)(g),                         \
    (__attribute__((address_space(3))) void*)(l), 16, 0, 0)

// inline-asm LDS read: invisible to compiler alias analysis, so it cannot
// insert a conservative s_waitcnt vmcnt(0) ordering vs global_load_lds.
static __device__ __forceinline__ short8 ds_read128(const bf16* p) {
    short8 r;
    asm volatile("ds_read_b128 %0, %1"
        : "=v"(r)
        : "v"((const __attribute__((address_space(3))) bf16*)p));
    return r;
}

// ---------------------------------------------------------------------------
// Unified prep: 6 weight transposes (fp32 [K,N] -> bf16 [N,K]) + bias pack
// ---------------------------------------------------------------------------
__global__ __launch_bounds__(256) void prep_all(
    const float* __restrict__ wq, const float* __restrict__ wk,
    const float* __restrict__ wv, const float* __restrict__ wo,
    const float* __restrict__ fc1w, const float* __restrict__ fc2w,
    const float* __restrict__ bq, const float* __restrict__ bk,
    const float* __restrict__ bv,
    bf16* __restrict__ wqkvt, bf16* __restrict__ wot,
    bf16* __restrict__ fc1t, bf16* __restrict__ fc2t,
    float* __restrict__ bqkv)
{
    const int bid = blockIdx.x;
    if (bid == 19200) {
        for (int i = threadIdx.x; i < DMODEL; i += 256) {
            bqkv[i]              = bq[i];
            bqkv[DMODEL + i]     = bk[i];
            bqkv[2 * DMODEL + i] = bv[i];
        }
        return;
    }
    const float* in;
    bf16* out;
    int K, N, n0, k0;
    if (bid < 6400) {
        const int mat = bid / 1600, rem = bid % 1600;
        K = DMODEL; N = DMODEL;
        n0 = (rem % 40) * 32; k0 = (rem / 40) * 32;
        switch (mat) {
            case 0:  in = wq; out = wqkvt; break;
            case 1:  in = wk; out = wqkvt + (size_t)DMODEL * DMODEL; break;
            case 2:  in = wv; out = wqkvt + (size_t)2 * DMODEL * DMODEL; break;
            default: in = wo; out = wot; break;
        }
    } else if (bid < 12800) {
        const int rem = bid - 6400;
        K = DMODEL; N = DFFN; in = fc1w; out = fc1t;
        n0 = (rem % 160) * 32; k0 = (rem / 160) * 32;
    } else {
        const int rem = bid - 12800;
        K = DFFN; N = DMODEL; in = fc2w; out = fc2t;
        n0 = (rem % 40) * 32; k0 = (rem / 40) * 32;
    }
    __shared__ float tile[32][33];
    const int tx = threadIdx.x & 31;
    const int ty = threadIdx.x >> 5;   // 0..7
    for (int i = 0; i < 32; i += 8)
        tile[ty + i][tx] = in[(size_t)(k0 + ty + i) * N + (n0 + tx)];
    __syncthreads();
    for (int i = 0; i < 32; i += 8)
        out[(size_t)(n0 + ty + i) * K + (k0 + tx)] = __float2bfloat16(tile[tx][ty + i]);
}

// ---------------------------------------------------------------------------
// LayerNorm over last dim (1280), one block (256 thr) per row, bf16 out
// ---------------------------------------------------------------------------
__global__ __launch_bounds__(256) void ln_bf16(
    const float* __restrict__ x, const float* __restrict__ sc,
    const float* __restrict__ of, bf16* __restrict__ out)
{
    const int row = blockIdx.x;
    const float* xr = x + (size_t)row * DMODEL;
    float v[5];
    float s = 0.f, s2 = 0.f;
    for (int i = 0; i < 5; ++i) {
        v[i] = xr[threadIdx.x + i * 256];
        s += v[i];
        s2 += v[i] * v[i];
    }
    for (int off = 1; off < 64; off <<= 1) {
        s  += __shfl_xor(s, off);
        s2 += __shfl_xor(s2, off);
    }
    __shared__ float red[2][4];
    const int wid = threadIdx.x >> 6;
    if ((threadIdx.x & 63) == 0) { red[0][wid] = s; red[1][wid] = s2; }
    __syncthreads();
    s  = red[0][0] + red[0][1] + red[0][2] + red[0][3];
    s2 = red[1][0] + red[1][1] + red[1][2] + red[1][3];
    const float mean = s * (1.0f / DMODEL);
    const float var  = s2 * (1.0f / DMODEL) - mean * mean;
    const float rstd = rsqrtf(var + 1e-5f);
    for (int i = 0; i < 5; ++i) {
        const int c = threadIdx.x + i * 256;
        const float y = (v[i] - mean) * rstd * sc[c] + of[c];
        out[(size_t)row * DMODEL + c] = __float2bfloat16(y);
    }
}

// ---------------------------------------------------------------------------
// Fused: x1 = P0 + P1 + bias + res;  h2 = LayerNorm(x1)*sc + of  (bf16)
// ---------------------------------------------------------------------------
__global__ __launch_bounds__(256) void reduce2_ln(
    const float* __restrict__ P, const float* __restrict__ bias,
    const float* __restrict__ res, float* __restrict__ x1,
    const float* __restrict__ sc, const float* __restrict__ of,
    bf16* __restrict__ h2)
{
    const int row = blockIdx.x;
    const size_t base = (size_t)row * DMODEL;
    const int MN = NROWS * DMODEL;
    float v[5];
    float s = 0.f, s2 = 0.f;
    for (int i = 0; i < 5; ++i) {
        const int c = threadIdx.x + i * 256;
        const float val = P[base + c] + P[MN + base + c] + bias[c] + res[base + c];
        v[i] = val;
        x1[base + c] = val;
        s += val;
        s2 += val * val;
    }
    for (int off = 1; off < 64; off <<= 1) {
        s  += __shfl_xor(s, off);
        s2 += __shfl_xor(s2, off);
    }
    __shared__ float red[2][4];
    const int wid = threadIdx.x >> 6;
    if ((threadIdx.x & 63) == 0) { red[0][wid] = s; red[1][wid] = s2; }
    __syncthreads();
    s  = red[0][0] + red[0][1] + red[0][2] + red[0][3];
    s2 = red[1][0] + red[1][1] + red[1][2] + red[1][3];
    const float mean = s * (1.0f / DMODEL);
    const float var  = s2 * (1.0f / DMODEL) - mean * mean;
    const float rstd = rsqrtf(var + 1e-5f);
    for (int i = 0; i < 5; ++i) {
        const int c = threadIdx.x + i * 256;
        const float y = (v[i] - mean) * rstd * sc[c] + of[c];
        h2[base + c] = __float2bfloat16(y);
    }
}

// ---------------------------------------------------------------------------
// gemm_trip: 128x256 tile, 72KB TRIPLE-buffer, counted vmcnt(3) (round-5
// kernel, verified).  Best measured FC1 (82.4us).  2 blocks/CU.
// ---------------------------------------------------------------------------
template <int EPI>
__global__ __launch_bounds__(512, 4) void gemm_trip(
    const bf16* __restrict__ A, const bf16* __restrict__ Bt,
    const float* __restrict__ bias,
    bf16* __restrict__ Cb, float* __restrict__ Cf,
    int M, int N, int K, int klen)
{
    __shared__ bf16 As[3][128][32];   // 24 KB
    __shared__ bf16 Bs[3][256][32];   // 48 KB
    const int m0 = blockIdx.x * 128;
    const int n0 = blockIdx.y * 256;
    const int z  = blockIdx.z;
    const int kbeg = z * klen;

    const int tid  = threadIdx.x;
    const int lane = tid & 63;
    const int wid  = tid >> 6;            // 0..7
    const int wm   = (wid >> 2) * 64;     // 2 m-groups of 64
    const int wn   = (wid & 3) * 64;      // 4 n-groups of 64
    const int l15  = lane & 15;
    const int lq   = lane >> 4;

    f32x4 acc[4][4];
    #pragma unroll
    for (int i = 0; i < 4; ++i)
        #pragma unroll
        for (int j = 0; j < 4; ++j)
            acc[i][j] = (f32x4){0.f, 0.f, 0.f, 0.f};

    const int cph  = lane & 3;                       // physical 16B chunk
    const int lrow = wid * 16 + (lane >> 2);         // 0..127
    const int cgl8 = (cph ^ ((lrow >> 1) & 3)) * 8;  // swizzled global chunk
    const int lcol = cph * 8;

    const bf16* aT = A  + (size_t)(m0 + lrow) * K + kbeg + cgl8;
    const bf16* bT = Bt + (size_t)(n0 + lrow) * K + kbeg + cgl8;
    const size_t rstep = (size_t)128 * K;

    GLDS(aT,              &As[0][lrow][lcol]);
    GLDS(bT,              &Bs[0][lrow][lcol]);
    GLDS(bT + rstep,      &Bs[0][lrow + 128][lcol]);
    GLDS(aT + 32,         &As[1][lrow][lcol]);
    GLDS(bT + 32,         &Bs[1][lrow][lcol]);
    GLDS(bT + 32 + rstep, &Bs[1][lrow + 128][lcol]);

    const int ca = (lq ^ ((l15 >> 1) & 3)) * 8;   // conflict-free frag chunk
    const int nIter = klen / 32;
    int buf = 0;
    for (int it = 0; it < nIter; ++it) {
        if (it + 1 < nIter) asm volatile("s_waitcnt vmcnt(3)" ::: "memory");
        else                asm volatile("s_waitcnt vmcnt(0)" ::: "memory");
        __builtin_amdgcn_s_barrier();

        if (it + 2 < nIter) {
            int bnx = buf + 2; if (bnx >= 3) bnx -= 3;
            const int k2 = (it + 2) * 32;
            GLDS(aT + k2,         &As[bnx][lrow][lcol]);
            GLDS(bT + k2,         &Bs[bnx][lrow][lcol]);
            GLDS(bT + k2 + rstep, &Bs[bnx][lrow + 128][lcol]);
        }

        short8 af[4], bfr[4];
        #pragma unroll
        for (int nt = 0; nt < 4; ++nt)
            bfr[nt] = ds_read128(&Bs[buf][wn + nt * 16 + l15][ca]);
        #pragma unroll
        for (int mt = 0; mt < 4; ++mt)
            af[mt] = ds_read128(&As[buf][wm + mt * 16 + l15][ca]);

        __builtin_amdgcn_s_setprio(1);
        asm volatile("s_waitcnt lgkmcnt(3)" ::: "memory");
        __builtin_amdgcn_sched_barrier(0);
        #pragma unroll
        for (int nt = 0; nt < 4; ++nt)
            acc[0][nt] = __builtin_amdgcn_mfma_f32_16x16x32_bf16(
                af[0], bfr[nt], acc[0][nt], 0, 0, 0);
        asm volatile("s_waitcnt lgkmcnt(2)" ::: "memory");
        __builtin_amdgcn_sched_barrier(0);
        #pragma unroll
        for (int nt = 0; nt < 4; ++nt)
            acc[1][nt] = __builtin_amdgcn_mfma_f32_16x16x32_bf16(
                af[1], bfr[nt], acc[1][nt], 0, 0, 0);
        asm volatile("s_waitcnt lgkmcnt(1)" ::: "memory");
        __builtin_amdgcn_sched_barrier(0);
        #pragma unroll
        for (int nt = 0; nt < 4; ++nt)
            acc[2][nt] = __builtin_amdgcn_mfma_f32_16x16x32_bf16(
                af[2], bfr[nt], acc[2][nt], 0, 0, 0);
        asm volatile("s_waitcnt lgkmcnt(0)" ::: "memory");
        __builtin_amdgcn_sched_barrier(0);
        #pragma unroll
        for (int nt = 0; nt < 4; ++nt)
            acc[3][nt] = __builtin_amdgcn_mfma_f32_16x16x32_bf16(
                af[3], bfr[nt], acc[3][nt], 0, 0, 0);
        __builtin_amdgcn_s_setprio(0);

        buf = (buf == 2) ? 0 : buf + 1;
    }

    float* Pf = Cf + (size_t)z * M * N;
    #pragma unroll
    for (int mt = 0; mt < 4; ++mt)
        #pragma unroll
        for (int nt = 0; nt < 4; ++nt)
            #pragma unroll
            for (int r = 0; r < 4; ++r) {
                const int row = m0 + wm + mt * 16 + lq * 4 + r;
                const int col = n0 + wn + nt * 16 + l15;
                if (EPI == 0) {
                    const float v = acc[mt][nt][r] + bias[col];
                    Cb[(size_t)row * N + col] = __float2bfloat16(v);
                } else if (EPI == 2) {
                    const float v = acc[mt][nt][r] + bias[col];
                    const float g = 0.5f * v * (1.0f + erff(v * 0.70710678118654752f));
                    Cb[(size_t)row * N + col] = __float2bfloat16(g);
                } else {
                    Pf[(size_t)row * N + col] = acc[mt][nt][r];
                }
            }
}

// ---------------------------------------------------------------------------
// gemm_db: 128x256 tile, 48KB DOUBLE-buffer, vmcnt(0)/iter, 3 blocks/CU
// (round-7 kernel, verified).  Collectively best for QKV/WO/FC2.
// ---------------------------------------------------------------------------
template <int EPI>
__global__ __launch_bounds__(512, 4) void gemm_db(
    const bf16* __restrict__ A, const bf16* __restrict__ Bt,
    const float* __restrict__ bias,
    bf16* __restrict__ Cb, float* __restrict__ Cf,
    int M, int N, int K, int klen)
{
    __shared__ bf16 As[2][128][32];   // 16 KB
    __shared__ bf16 Bs[2][256][32];   // 32 KB
    const int m0 = blockIdx.x * 128;
    const int n0 = blockIdx.y * 256;
    const int z  = blockIdx.z;
    const int kbeg = z * klen;

    const int tid  = threadIdx.x;
    const int lane = tid & 63;
    const int wid  = tid >> 6;            // 0..7
    const int wm   = (wid >> 2) * 64;     // 2 m-groups of 64
    const int wn   = (wid & 3) * 64;      // 4 n-groups of 64
    const int l15  = lane & 15;
    const int lq   = lane >> 4;

    f32x4 acc[4][4];
    #pragma unroll
    for (int i = 0; i < 4; ++i)
        #pragma unroll
        for (int j = 0; j < 4; ++j)
            acc[i][j] = (f32x4){0.f, 0.f, 0.f, 0.f};

    const int cph  = lane & 3;                       // physical 16B chunk
    const int lrow = wid * 16 + (lane >> 2);         // 0..127
    const int cgl8 = (cph ^ ((lrow >> 1) & 3)) * 8;  // swizzled global chunk
    const int lcol = cph * 8;

    const bf16* aT = A  + (size_t)(m0 + lrow) * K + kbeg + cgl8;
    const bf16* bT = Bt + (size_t)(n0 + lrow) * K + kbeg + cgl8;
    const size_t rstep = (size_t)128 * K;

    GLDS(aT,         &As[0][lrow][lcol]);
    GLDS(bT,         &Bs[0][lrow][lcol]);
    GLDS(bT + rstep, &Bs[0][lrow + 128][lcol]);

    const int ca = (lq ^ ((l15 >> 1) & 3)) * 8;   // conflict-free frag chunk
    const int nIter = klen / 32;
    int buf = 0;
    for (int it = 0; it < nIter; ++it) {
        asm volatile("s_waitcnt vmcnt(0)" ::: "memory");
        __builtin_amdgcn_s_barrier();

        if (it + 1 < nIter) {
            const int k1 = (it + 1) * 32;
            GLDS(aT + k1,         &As[buf ^ 1][lrow][lcol]);
            GLDS(bT + k1,         &Bs[buf ^ 1][lrow][lcol]);
            GLDS(bT + k1 + rstep, &Bs[buf ^ 1][lrow + 128][lcol]);
        }

        short8 af[4], bfr[4];
        #pragma unroll
        for (int nt = 0; nt < 4; ++nt)
            bfr[nt] = ds_read128(&Bs[buf][wn + nt * 16 + l15][ca]);
        #pragma unroll
        for (int mt = 0; mt < 4; ++mt)
            af[mt] = ds_read128(&As[buf][wm + mt * 16 + l15][ca]);

        __builtin_amdgcn_s_setprio(1);
        asm volatile("s_waitcnt lgkmcnt(3)" ::: "memory");
        __builtin_amdgcn_sched_barrier(0);
        #pragma unroll
        for (int nt = 0; nt < 4; ++nt)
            acc[0][nt] = __builtin_amdgcn_mfma_f32_16x16x32_bf16(
                af[0], bfr[nt], acc[0][nt], 0, 0, 0);
        asm volatile("s_waitcnt lgkmcnt(2)" ::: "memory");
        __builtin_amdgcn_sched_barrier(0);
        #pragma unroll
        for (int nt = 0; nt < 4; ++nt)
            acc[1][nt] = __builtin_amdgcn_mfma_f32_16x16x32_bf16(
                af[1], bfr[nt], acc[1][nt], 0, 0, 0);
        asm volatile("s_waitcnt lgkmcnt(1)" ::: "memory");
        __builtin_amdgcn_sched_barrier(0);
        #pragma unroll
        for (int nt = 0; nt < 4; ++nt)
            acc[2][nt] = __builtin_amdgcn_mfma_f32_16x16x32_bf16(
                af[2], bfr[nt], acc[2][nt], 0, 0, 0);
        asm volatile("s_waitcnt lgkmcnt(0)" ::: "memory");
        __builtin_amdgcn_sched_barrier(0);
        #pragma unroll
        for (int nt = 0; nt < 4; ++nt)
            acc[3][nt] = __builtin_amdgcn_mfma_f32_16x16x32_bf16(
                af[3], bfr[nt], acc[3][nt], 0, 0, 0);
        __builtin_amdgcn_s_setprio(0);

        buf ^= 1;
    }

    float* Pf = Cf + (size_t)z * M * N;
    #pragma unroll
    for (int mt = 0; mt < 4; ++mt)
        #pragma unroll
        for (int nt = 0; nt < 4; ++nt)
            #pragma unroll
            for (int r = 0; r < 4; ++r) {
                const int row = m0 + wm + mt * 16 + lq * 4 + r;
                const int col = n0 + wn + nt * 16 + l15;
                if (EPI == 0) {
                    const float v = acc[mt][nt][r] + bias[col];
                    Cb[(size_t)row * N + col] = __float2bfloat16(v);
                } else if (EPI == 2) {
                    const float v = acc[mt][nt][r] + bias[col];
                    const float g = 0.5f * v * (1.0f + erff(v * 0.70710678118654752f));
                    Cb[(size_t)row * N + col] = __float2bfloat16(g);
                } else {
                    Pf[(size_t)row * N + col] = acc[mt][nt][r];
                }
            }
}

// ---------------------------------------------------------------------------
// split-K=2 reduce: out = P0 + P1 + bias + res   (float4 vectorized)
// ---------------------------------------------------------------------------
__global__ __launch_bounds__(256) void reduce2(
    const float* __restrict__ P, const float* __restrict__ bias,
    const float* __restrict__ res, float* __restrict__ out, int MN, int N)
{
    const int i = (blockIdx.x * 256 + threadIdx.x) * 4;
    if (i >= MN) return;
    const float4 p0 = *(const float4*)(P + i);
    const float4 p1 = *(const float4*)(P + MN + i);
    const float4 r  = *(const float4*)(res + i);
    const float4 b  = *(const float4*)(bias + (i % N));
    float4 o;
    o.x = p0.x + p1.x + r.x + b.x;
    o.y = p0.y + p1.y + r.y + b.y;
    o.z = p0.z + p1.z + r.z + b.z;
    o.w = p0.w + p1.w + r.w + b.w;
    *(float4*)(out + i) = o;
}

// ---------------------------------------------------------------------------
// Flash attention v3 (unchanged): transposed-S formulation.
// ---------------------------------------------------------------------------
__global__ __launch_bounds__(256) void flash_attn(
    const bf16* __restrict__ qb, const bf16* __restrict__ kb,
    const bf16* __restrict__ vb, bf16* __restrict__ ob, int ldq)
{
    __shared__ bf16 Ks[2][64][64];    // 16 KB  [kv][d]
    __shared__ bf16 Vt[64][64];       // 8 KB   [d][kv]
    __shared__ bf16 Ps[4][16][64];    // 8 KB   per-wave P^T as [q][kv]

    const int bh = blockIdx.y;
    const int b  = bh / NHEAD;
    const int hh = bh % NHEAD;
    const int q0 = blockIdx.x * 64;
    const int tid  = threadIdx.x;
    const int lane = tid & 63;
    const int wid  = tid >> 6;
    const int l15  = lane & 15;
    const int lq   = lane >> 4;
    const int key  = l15 & 7;

    short8 qf[2];
    {
        const bf16* qp = qb + (size_t)(b * SEQ + q0 + wid * 16 + l15) * ldq
                         + hh * HDIM + lq * 8;
        for (int kk = 0; kk < 2; ++kk) {
            union { short8 v; bf16 h[8]; } u;
            u.v = *(const short8*)(qp + kk * 32);
            for (int j = 0; j < 8; ++j)
                u.h[j] = __float2bfloat16(__bfloat162float(u.h[j]) * 0.125f);
            qf[kk] = u.v;
        }
    }

    f32x4 o[4];   // O^T: row d = dt*16 + lq*4 + r, col q = l15
    for (int dt = 0; dt < 4; ++dt) o[dt] = (f32x4){0.f, 0.f, 0.f, 0.f};
    float lsum = 0.f;

    const int krow  = wid * 8 + (lane >> 3);
    const int kcgl8 = ((lane & 7) ^ (krow & 7)) * 8;
    const int kcph8 = (lane & 7) * 8;
    const int vd0  = (tid & 15) * 4;
    const int vkv0 = (tid >> 4) * 4;

    const bf16* kBase = kb + (size_t)(b * SEQ + krow) * ldq + hh * HDIM + kcgl8;
    const bf16* vBase = vb + (size_t)(b * SEQ + vkv0) * ldq + hh * HDIM + vd0;

    GLDS(kBase,                    &Ks[0][krow][kcph8]);
    GLDS(kBase + (size_t)32 * ldq, &Ks[0][krow + 32][kcph8]);
    u16x4 vr[4];
    for (int j = 0; j < 4; ++j)
        vr[j] = *(const u16x4*)(vBase + (size_t)j * ldq);

    const int nIter = SEQ / 64;
    for (int it = 0; it < nIter; ++it) {
        const int buf = it & 1;
        __syncthreads();
        for (int i = 0; i < 4; ++i) {
            u16x4 w = { vr[0][i], vr[1][i], vr[2][i], vr[3][i] };
            const int p = ((vkv0 >> 3) ^ ((vd0 + i) & 7)) * 8 + (vkv0 & 7);
            *(u16x4*)(&Vt[vd0 + i][p]) = w;
        }
        __syncthreads();

        if (it + 1 < nIter) {
            const size_t off = (size_t)(it + 1) * 64 * ldq;
            GLDS(kBase + off,                    &Ks[buf ^ 1][krow][kcph8]);
            GLDS(kBase + off + (size_t)32 * ldq, &Ks[buf ^ 1][krow + 32][kcph8]);
            for (int j = 0; j < 4; ++j)
                vr[j] = *(const u16x4*)(vBase + off + (size_t)j * ldq);
        }

        // ---- S^T = K Q^T ----
        for (int mt = 0; mt < 4; ++mt) {
            const bf16* kp = &Ks[buf][mt * 16 + l15][0];
            const short8 kf0 = *(const short8*)(kp + ((0 + lq) ^ key) * 8);
            const short8 kf1 = *(const short8*)(kp + ((4 + lq) ^ key) * 8);
            f32x4 a = (f32x4){0.f, 0.f, 0.f, 0.f};
            a = __builtin_amdgcn_mfma_f32_16x16x32_bf16(kf0, qf[0], a, 0, 0, 0);
            a = __builtin_amdgcn_mfma_f32_16x16x32_bf16(kf1, qf[1], a, 0, 0, 0);
            union { u16x4 v; bf16 h[4]; } pk;
            for (int r = 0; r < 4; ++r) {
                const float p = __expf(a[r]);
                lsum += p;
                pk.h[r] = __float2bfloat16(p);
            }
            const int pc = ((mt * 2 + (lq >> 1)) ^ key) * 8 + (lq & 1) * 4;
            *(u16x4*)(&Ps[wid][l15][pc]) = pk.v;
        }

        // ---- O^T += V^T P^T ----
        for (int kk = 0; kk < 2; ++kk) {
            const short8 pf = *(const short8*)(
                &Ps[wid][l15][((lq + 4 * kk) ^ key) * 8]);
            for (int dt = 0; dt < 4; ++dt) {
                const short8 vf = *(const short8*)(
                    &Vt[dt * 16 + l15][((lq + 4 * kk) ^ key) * 8]);
                o[dt] = __builtin_amdgcn_mfma_f32_16x16x32_bf16(
                    vf, pf, o[dt], 0, 0, 0);
            }
        }
    }

    lsum += __shfl_xor(lsum, 16);
    lsum += __shfl_xor(lsum, 32);
    const float inv_l = 1.0f / lsum;

    const size_t qrow = (size_t)(b * SEQ + q0 + wid * 16 + l15);
    for (int dt = 0; dt < 4; ++dt) {
        union { u16x4 v; bf16 h[4]; } w;
        for (int r = 0; r < 4; ++r)
            w.h[r] = __float2bfloat16(o[dt][r] * inv_l);
        *(u16x4*)(ob + qrow * DMODEL + hh * HDIM + dt * 16 + lq * 4) = w.v;
    }
}

// ---------------------------------------------------------------------------
extern "C" void kernel_launch(void* const* d_in, const int* in_sizes, int n_in,
                              void* d_out, int out_size, void* d_ws, size_t ws_size,
                              hipStream_t stream)
{
    (void)in_sizes; (void)n_in; (void)out_size; (void)ws_size;
    const float* x    = (const float*)d_in[0];
    const float* ln1s = (const float*)d_in[1];
    const float* ln1o = (const float*)d_in[2];
    const float* wq   = (const float*)d_in[3];
    const float* bq   = (const float*)d_in[4];
    const float* wk   = (const float*)d_in[5];
    const float* bk   = (const float*)d_in[6];
    const float* wv   = (const float*)d_in[7];
    const float* bv   = (const float*)d_in[8];
    const float* wo   = (const float*)d_in[9];
    const float* bo   = (const float*)d_in[10];
    const float* ln2s = (const float*)d_in[11];
    const float* ln2o = (const float*)d_in[12];
    const float* fc1w = (const float*)d_in[13];
    const float* fc1b = (const float*)d_in[14];
    const float* fc2w = (const float*)d_in[15];
    const float* fc2b = (const float*)d_in[16];
    float* out = (float*)d_out;

    char* wp = (char*)d_ws;
    auto alloc = [&](size_t n) { char* p = wp; wp += (n + 255) & ~(size_t)255; return p; };
    bf16*  wqkvt = (bf16*)alloc((size_t)3 * DMODEL * DMODEL * 2);
    bf16*  wot   = (bf16*)alloc((size_t)DMODEL * DMODEL * 2);
    bf16*  fc1t  = (bf16*)alloc((size_t)DFFN * DMODEL * 2);    // [5120][1280]
    bf16*  fc2t  = (bf16*)alloc((size_t)DMODEL * DFFN * 2);    // [1280][5120]
    float* bqkv  = (float*)alloc((size_t)3 * DMODEL * 4);
    // region A: h | qkv | attn ; partials (split-K=2, 41.94 MB) alias h+qkv
    char*  regA  = alloc((size_t)NROWS * DMODEL * 2      // h
                       + (size_t)NROWS * 3 * DMODEL * 2  // qkv
                       + (size_t)NROWS * DMODEL * 2);    // attn
    bf16*  h     = (bf16*)regA;
    bf16*  qkv   = (bf16*)(regA + (size_t)NROWS * DMODEL * 2);
    bf16*  attn  = (bf16*)(regA + (size_t)NROWS * 4 * DMODEL * 2);
    float* part  = (float*)regA;                         // 2 * NROWS*DMODEL f32
    bf16*  h2    = (bf16*)alloc((size_t)NROWS * DMODEL * 2);
    bf16*  g     = (bf16*)alloc((size_t)NROWS * DFFN * 2);
    float* x1    = out;   // post-attention residual lives in d_out

    prep_all<<<19201, 256, 0, stream>>>(
        wq, wk, wv, wo, fc1w, fc2w, bq, bk, bv,
        wqkvt, wot, fc1t, fc2t, bqkv);

    ln_bf16<<<NROWS, 256, 0, stream>>>(x, ln1s, ln1o, h);

    // fused QKV (db variant, 480 blocks, 3 blk/CU one round)
    gemm_db<0><<<dim3(NROWS / 128, 3 * DMODEL / 256, 1), 512, 0, stream>>>(
        h, wqkvt, bqkv, qkv, nullptr, NROWS, 3 * DMODEL, DMODEL, DMODEL);

    flash_attn<<<dim3(SEQ / 64, BATCH * NHEAD), 256, 0, stream>>>(
        qkv, qkv + DMODEL, qkv + 2 * DMODEL, attn, 3 * DMODEL);

    // WO split-K=2 (db variant, 320 blocks), then fused reduce+LN2
    gemm_db<3><<<dim3(NROWS / 128, DMODEL / 256, 2), 512, 0, stream>>>(
        attn, wot, nullptr, nullptr, part, NROWS, DMODEL, DMODEL, DMODEL / 2);
    reduce2_ln<<<NROWS, 256, 0, stream>>>(part, bo, x, x1, ln2s, ln2o, h2);

    // FC1 + exact GELU (trip variant — best measured FC1, 640 blocks)
    gemm_trip<2><<<dim3(NROWS / 128, DFFN / 256, 1), 512, 0, stream>>>(
        h2, fc1t, fc1b, g, nullptr, NROWS, DFFN, DMODEL, DMODEL);

    // FC2 split-K=2 (db variant, 320 blocks), then reduce
    gemm_db<3><<<dim3(NROWS / 128, DMODEL / 256, 2), 512, 0, stream>>>(
        g, fc2t, nullptr, nullptr, part, NROWS, DMODEL, DFFN, DFFN / 2);
    reduce2<<<(NROWS * DMODEL / 4 + 255) / 256, 256, 0, stream>>>(
        part, fc2b, x1, out, NROWS * DMODEL, DMODEL);
}